// Round 5
// baseline (370.926 us; speedup 1.0000x reference)
//
#include <hip/hip_runtime.h>
#include <hip/hip_bf16.h>

typedef __attribute__((ext_vector_type(8))) short short8;
typedef __attribute__((ext_vector_type(8))) unsigned short ushort8;
typedef __attribute__((ext_vector_type(4))) float f32x4;

#define BDIM 1024
#define SEQ  2048
#define NHD  16
#define NEGBIG (-1.0e30f)

__device__ __forceinline__ unsigned short f2bf(float x) {
  union { __hip_bfloat16 h; unsigned short u; } cv;
  cv.h = __float2bfloat16(x);
  return cv.u;
}

// ---------------- f32 -> bf16 conversion (X), 8 elems/lane ----------------
__global__ __launch_bounds__(256) void cvt_f32_bf16(const float* __restrict__ src,
                                                    unsigned short* __restrict__ dst) {
  int i = (blockIdx.x * 256 + threadIdx.x) * 8;
  float4 a = *(const float4*)(src + i);
  float4 b = *(const float4*)(src + i + 4);
  ushort8 o;
  o[0] = f2bf(a.x); o[1] = f2bf(a.y); o[2] = f2bf(a.z); o[3] = f2bf(a.w);
  o[4] = f2bf(b.x); o[5] = f2bf(b.y); o[6] = f2bf(b.z); o[7] = f2bf(b.w);
  *(ushort8*)(dst + i) = o;
}

// ---------------- weight transpose+convert: dst[n][k] = bf16(src[k][n]) ----------------
__global__ __launch_bounds__(256) void wtrans(const float* __restrict__ src,
                                              unsigned short* __restrict__ dst) {
  __shared__ float t[32][33];
  int tx = threadIdx.x, ty = threadIdx.y;
  int c0 = blockIdx.x * 32, r0 = blockIdx.y * 32;
  for (int i = ty; i < 32; i += 8)
    t[i][tx] = src[(size_t)(r0 + i) * BDIM + c0 + tx];
  __syncthreads();
  for (int i = ty; i < 32; i += 8)
    dst[(size_t)(c0 + i) * BDIM + r0 + tx] = f2bf(t[tx][i]);
}

// ---------------- GEMM: C[M][1024] = A[M][1024] * W, given WT[n][k] (bf16 in) --------
// tile 128x128, BK=64, 4 waves (2x2), each wave 64x64 via 4x4 mfma 16x16x32 frags.
// Reg-staged LDS, XOR swizzle applied identically on write and read addresses.
// F32OUT: write f32 (final projection into d_out) vs bf16 (intermediates).
template <bool F32OUT>
__global__ __launch_bounds__(256) void gemm_bt(const unsigned short* __restrict__ A,
                                               const unsigned short* __restrict__ BT,
                                               void* __restrict__ Cv) {
  __shared__ __align__(16) unsigned short As[128 * 64];
  __shared__ __align__(16) unsigned short Bs[128 * 64];
  const int tid = threadIdx.x;
  const int lane = tid & 63;
  const int w = tid >> 6;
  const int wr = w >> 1, wc = w & 1;
  const int m0 = blockIdx.x * 128;
  const int n0 = blockIdx.y * 128;
  const int l15 = lane & 15, lg = lane >> 4;

  f32x4 acc[4][4] = {};

  for (int k0 = 0; k0 < BDIM; k0 += 64) {
    for (int j = 0; j < 4; ++j) {
      int o = (w * 4 + j) * 1024 + lane * 16;
      int row = o >> 7;
      int kb = o & 127;
      ushort8 av = *(const ushort8*)(A + (size_t)(m0 + row) * BDIM + k0 + (kb >> 1));
      ushort8 bv = *(const ushort8*)(BT + (size_t)(n0 + row) * BDIM + k0 + (kb >> 1));
      int dst = row * 128 + (kb ^ ((row & 7) << 4));
      *(ushort8*)((char*)As + dst) = av;
      *(ushort8*)((char*)Bs + dst) = bv;
    }
    __syncthreads();
    for (int ks = 0; ks < 64; ks += 32) {
      int kb = (ks + lg * 8) * 2;
      short8 a[4], b[4];
      for (int mi = 0; mi < 4; ++mi) {
        int row = wr * 64 + mi * 16 + l15;
        a[mi] = *(const short8*)((const char*)As + row * 128 + (kb ^ ((row & 7) << 4)));
      }
      for (int nj = 0; nj < 4; ++nj) {
        int row = wc * 64 + nj * 16 + l15;
        b[nj] = *(const short8*)((const char*)Bs + row * 128 + (kb ^ ((row & 7) << 4)));
      }
      for (int mi = 0; mi < 4; ++mi)
        for (int nj = 0; nj < 4; ++nj)
          acc[mi][nj] = __builtin_amdgcn_mfma_f32_16x16x32_bf16(a[mi], b[nj], acc[mi][nj], 0, 0, 0);
    }
    __syncthreads();
  }
  for (int mi = 0; mi < 4; ++mi)
    for (int nj = 0; nj < 4; ++nj) {
      int m = m0 + wr * 64 + mi * 16 + lg * 4;
      int n = n0 + wc * 64 + nj * 16 + l15;
      for (int r = 0; r < 4; ++r) {
        if constexpr (F32OUT)
          ((float*)Cv)[(size_t)(m + r) * BDIM + n] = acc[mi][nj][r];
        else
          ((unsigned short*)Cv)[(size_t)(m + r) * BDIM + n] = f2bf(acc[mi][nj][r]);
      }
    }
}

// ---------------- flash attention (causal), Q/K/V/O all [B*S][1024] bf16, head h*64 ----
// block: 128 q-rows of one (b,h); 4 waves x 32 rows; KV tiles of 64.
__global__ __launch_bounds__(256) void attn(const unsigned short* __restrict__ Qg,
                                            const unsigned short* __restrict__ Kg,
                                            const unsigned short* __restrict__ Vg,
                                            unsigned short* __restrict__ Og) {
  __shared__ __align__(16) unsigned short Qs[128 * 64];
  __shared__ __align__(16) unsigned short Ks[64 * 64];
  __shared__ __align__(16) unsigned short VTs[64 * 64];
  __shared__ __align__(16) unsigned short Ps[128 * 64];

  const int tid = threadIdx.x;
  const int lane = tid & 63;
  const int w = tid >> 6;
  const int l15 = lane & 15, lg = lane >> 4;
  const int q0 = blockIdx.x * 128;
  const int bh = blockIdx.y;
  const size_t base = ((size_t)(bh >> 4) * SEQ) * BDIM + (size_t)(bh & 15) * 64;

  // stage Q tile [128][64] (reg-staged, swizzled LDS writes)
  for (int j = 0; j < 4; ++j) {
    int o = (w * 4 + j) * 1024 + lane * 16;
    int row = o >> 7;
    int kb = o & 127;
    ushort8 qv = *(const ushort8*)(Qg + base + (size_t)(q0 + row) * BDIM + (kb >> 1));
    *(ushort8*)((char*)Qs + row * 128 + (kb ^ ((row & 7) << 4))) = qv;
  }
  __syncthreads();

  short8 qf[2][2];
  for (int mi = 0; mi < 2; ++mi)
    for (int ks = 0; ks < 2; ++ks) {
      int row = w * 32 + mi * 16 + l15;
      int kb = (ks * 32 + lg * 8) * 2;
      qf[mi][ks] = *(const short8*)((const char*)Qs + row * 128 + (kb ^ ((row & 7) << 4)));
    }

  float mrow[2][4], lrow[2][4];
  f32x4 oacc[2][4] = {};
  for (int mi = 0; mi < 2; ++mi)
    for (int r = 0; r < 4; ++r) { mrow[mi][r] = NEGBIG; lrow[mi][r] = 0.f; }

  const int ntiles = (q0 >> 6) + 2;
  for (int t = 0; t < ntiles; ++t) {
    const int kv0 = t * 64;
    // stage K tile [64][64] (reg-staged, swizzled)
    for (int j = 0; j < 2; ++j) {
      int o = (w * 2 + j) * 1024 + lane * 16;
      int row = o >> 7;
      int kb = o & 127;
      ushort8 kv8 = *(const ushort8*)(Kg + base + (size_t)(kv0 + row) * BDIM + (kb >> 1));
      *(ushort8*)((char*)Ks + row * 128 + (kb ^ ((row & 7) << 4))) = kv8;
    }
    // stage V transposed: VTs[d][kv] (reg-staged, swizzled writes)
    {
      int kv = tid >> 2, dc = tid & 3;
      const unsigned short* vsrc = Vg + base + (size_t)(kv0 + kv) * BDIM + dc * 16;
      ushort8 v0 = *(const ushort8*)vsrc;
      ushort8 v1 = *(const ushort8*)(vsrc + 8);
      for (int e = 0; e < 8; ++e) {
        int d = dc * 16 + e;
        *(unsigned short*)((char*)VTs + d * 128 + ((kv * 2) ^ ((d & 7) << 4))) = v0[e];
      }
      for (int e = 0; e < 8; ++e) {
        int d = dc * 16 + 8 + e;
        *(unsigned short*)((char*)VTs + d * 128 + ((kv * 2) ^ ((d & 7) << 4))) = v1[e];
      }
    }
    __syncthreads();

    if (kv0 <= q0 + w * 32 + 31) {  // wave-uniform causal skip
      // QK^T -> s[mi][kvj] (C-layout: row=4*lg+r, col=l15)
      f32x4 s[2][4];
      for (int kvj = 0; kvj < 4; ++kvj) {
        int row = kvj * 16 + l15;
        int kb0 = (lg * 8) * 2;
        int kb1 = (32 + lg * 8) * 2;
        short8 kf0 = *(const short8*)((const char*)Ks + row * 128 + (kb0 ^ ((row & 7) << 4)));
        short8 kf1 = *(const short8*)((const char*)Ks + row * 128 + (kb1 ^ ((row & 7) << 4)));
        for (int mi = 0; mi < 2; ++mi) {
          f32x4 z = {};
          z = __builtin_amdgcn_mfma_f32_16x16x32_bf16(qf[mi][0], kf0, z, 0, 0, 0);
          z = __builtin_amdgcn_mfma_f32_16x16x32_bf16(qf[mi][1], kf1, z, 0, 0, 0);
          s[mi][kvj] = z;
        }
      }
      // scale + causal mask + online softmax (16-lane group reductions, finite sentinels)
      for (int mi = 0; mi < 2; ++mi) {
        for (int r = 0; r < 4; ++r) {
          int q = q0 + w * 32 + mi * 16 + lg * 4 + r;
          float mx = NEGBIG;
          for (int kvj = 0; kvj < 4; ++kvj) {
            int kv = kv0 + kvj * 16 + l15;
            float v = s[mi][kvj][r] * 0.125f;
            if (kv > q) v = NEGBIG;
            s[mi][kvj][r] = v;
            mx = fmaxf(mx, v);
          }
          for (int sh = 1; sh < 16; sh <<= 1) mx = fmaxf(mx, __shfl_xor(mx, sh));
          float mnew = fmaxf(mrow[mi][r], mx);
          float sc = __expf(mrow[mi][r] - mnew);  // arg <= 0 always
          mrow[mi][r] = mnew;
          float rs = 0.f;
          for (int kvj = 0; kvj < 4; ++kvj) {
            float p = __expf(s[mi][kvj][r] - mnew);  // masked: exp(~-1e30) == 0
            s[mi][kvj][r] = p;
            rs += p;
          }
          for (int sh = 1; sh < 16; sh <<= 1) rs += __shfl_xor(rs, sh);
          lrow[mi][r] = lrow[mi][r] * sc + rs;
          for (int di = 0; di < 4; ++di) oacc[mi][di][r] *= sc;
        }
      }
      // P -> LDS (bf16, swizzled; own wave's rows only)
      for (int mi = 0; mi < 2; ++mi)
        for (int kvj = 0; kvj < 4; ++kvj)
          for (int r = 0; r < 4; ++r) {
            int row = w * 32 + mi * 16 + lg * 4 + r;
            int col2 = (kvj * 16 + l15) * 2;
            *(unsigned short*)((char*)Ps + row * 128 + (col2 ^ ((row & 7) << 4))) =
                f2bf(s[mi][kvj][r]);
          }
      // PV: O[q][d] += P[q][kv] * V[kv][d]
      short8 pa[2][2];
      for (int mi = 0; mi < 2; ++mi)
        for (int ks = 0; ks < 2; ++ks) {
          int row = w * 32 + mi * 16 + l15;
          int kb = (ks * 32 + lg * 8) * 2;
          pa[mi][ks] = *(const short8*)((const char*)Ps + row * 128 + (kb ^ ((row & 7) << 4)));
        }
      for (int di = 0; di < 4; ++di) {
        int row = di * 16 + l15;
        int kb0 = (lg * 8) * 2;
        int kb1 = (32 + lg * 8) * 2;
        short8 vf0 = *(const short8*)((const char*)VTs + row * 128 + (kb0 ^ ((row & 7) << 4)));
        short8 vf1 = *(const short8*)((const char*)VTs + row * 128 + (kb1 ^ ((row & 7) << 4)));
        for (int mi = 0; mi < 2; ++mi) {
          oacc[mi][di] = __builtin_amdgcn_mfma_f32_16x16x32_bf16(pa[mi][0], vf0, oacc[mi][di], 0, 0, 0);
          oacc[mi][di] = __builtin_amdgcn_mfma_f32_16x16x32_bf16(pa[mi][1], vf1, oacc[mi][di], 0, 0, 0);
        }
      }
    }
    __syncthreads();
  }

  // normalize + write O (merged-head layout [B*S][1024])
  for (int mi = 0; mi < 2; ++mi)
    for (int r = 0; r < 4; ++r) {
      int qrow = q0 + w * 32 + mi * 16 + lg * 4 + r;
      float inv = 1.0f / lrow[mi][r];
      for (int di = 0; di < 4; ++di) {
        int d = di * 16 + l15;
        Og[base + (size_t)qrow * BDIM + d] = f2bf(oacc[mi][di][r] * inv);
      }
    }
}

extern "C" void kernel_launch(void* const* d_in, const int* in_sizes, int n_in,
                              void* d_out, int out_size, void* d_ws, size_t ws_size,
                              hipStream_t stream) {
  // Inputs f32 (in_npz 46.7MB == 12.58M elems * 4B at ~7% deflate; bf16 raw would be
  // only 25.2MB -- npz cannot inflate). Output f32 per reference dtype.
  const float* X  = (const float*)d_in[0];
  const float* Wq = (const float*)d_in[1];
  const float* Wk = (const float*)d_in[2];
  const float* Wv = (const float*)d_in[3];
  const float* Wo = (const float*)d_in[4];

  const size_t WSZ = (size_t)1024 * 1024;  // weight elems
  const size_t MSZ = (size_t)8192 * 1024;  // activation elems
  const size_t need = (4 * WSZ + 4 * MSZ) * 2;  // 72 MB
  if (ws_size < need) return;  // diagnostic: error == 3.8125 exactly -> ws too small

  unsigned short* ws = (unsigned short*)d_ws;
  unsigned short* WqT = ws;
  unsigned short* WkT = WqT + WSZ;
  unsigned short* WvT = WkT + WSZ;
  unsigned short* WoT = WvT + WSZ;
  unsigned short* Qw  = WoT + WSZ;
  unsigned short* Kw  = Qw + MSZ;
  unsigned short* Vw  = Kw + MSZ;
  unsigned short* Ow  = Vw + MSZ;
  // X-bf16 scratch lives in d_out (f32 out buffer is 32MB >= 16MB needed; Xb is
  // fully consumed before the final GEMM overwrites d_out).
  unsigned short* Xb  = (unsigned short*)d_out;

  dim3 tb(32, 8);
  dim3 tg(32, 32);
  wtrans<<<tg, tb, 0, stream>>>(Wq, WqT);
  wtrans<<<tg, tb, 0, stream>>>(Wk, WkT);
  wtrans<<<tg, tb, 0, stream>>>(Wv, WvT);
  wtrans<<<tg, tb, 0, stream>>>(Wo, WoT);

  cvt_f32_bf16<<<(8192 * 1024) / (256 * 8), 256, 0, stream>>>(X, Xb);

  dim3 gg(64, 8);
  gemm_bt<false><<<gg, 256, 0, stream>>>(Xb, WqT, Qw);
  gemm_bt<false><<<gg, 256, 0, stream>>>(Xb, WkT, Kw);
  gemm_bt<false><<<gg, 256, 0, stream>>>(Xb, WvT, Vw);

  attn<<<dim3(16, 64), 256, 0, stream>>>(Qw, Kw, Vw, Ow);

  gemm_bt<true><<<gg, 256, 0, stream>>>(Ow, WoT, d_out);
}

// Round 7
// 279.921 us; speedup vs baseline: 1.3251x; 1.3251x over previous
//
#include <hip/hip_runtime.h>
#include <hip/hip_bf16.h>

typedef __attribute__((ext_vector_type(8))) short short8;
typedef __attribute__((ext_vector_type(8))) unsigned short ushort8;
typedef __attribute__((ext_vector_type(4))) unsigned short bf16x4;
typedef __attribute__((ext_vector_type(4))) float f32x4;

#define BDIM 1024
#define SEQ  2048
#define NHD  16
#define NEGBIG (-1.0e30f)

__device__ __forceinline__ unsigned short f2bf(float x) {
  union { __hip_bfloat16 h; unsigned short u; } cv;
  cv.h = __float2bfloat16(x);
  return cv.u;
}

// ---------------- f32 -> bf16 conversion (X), 8 elems/lane ----------------
__global__ __launch_bounds__(256) void cvt_f32_bf16(const float* __restrict__ src,
                                                    unsigned short* __restrict__ dst) {
  int i = (blockIdx.x * 256 + threadIdx.x) * 8;
  float4 a = *(const float4*)(src + i);
  float4 b = *(const float4*)(src + i + 4);
  ushort8 o;
  o[0] = f2bf(a.x); o[1] = f2bf(a.y); o[2] = f2bf(a.z); o[3] = f2bf(a.w);
  o[4] = f2bf(b.x); o[5] = f2bf(b.y); o[6] = f2bf(b.z); o[7] = f2bf(b.w);
  *(ushort8*)(dst + i) = o;
}

// ---------------- weight transpose+convert: dst[n][k] = bf16(src[k][n]) ----------------
__global__ __launch_bounds__(256) void wtrans(const float* __restrict__ src,
                                              unsigned short* __restrict__ dst) {
  __shared__ float t[32][33];
  int tx = threadIdx.x, ty = threadIdx.y;
  int c0 = blockIdx.x * 32, r0 = blockIdx.y * 32;
  for (int i = ty; i < 32; i += 8)
    t[i][tx] = src[(size_t)(r0 + i) * BDIM + c0 + tx];
  __syncthreads();
  for (int i = ty; i < 32; i += 8)
    dst[(size_t)(c0 + i) * BDIM + r0 + tx] = f2bf(t[tx][i]);
}

// ---------------- GEMM: C[M][1024] = A[M][1024] * W, given WT[n][k] (bf16 in) --------
template <bool F32OUT>
__global__ __launch_bounds__(256) void gemm_bt(const unsigned short* __restrict__ A,
                                               const unsigned short* __restrict__ BT,
                                               void* __restrict__ Cv) {
  __shared__ __align__(16) unsigned short As[128 * 64];
  __shared__ __align__(16) unsigned short Bs[128 * 64];
  const int tid = threadIdx.x;
  const int lane = tid & 63;
  const int w = tid >> 6;
  const int wr = w >> 1, wc = w & 1;
  const int m0 = blockIdx.x * 128;
  const int n0 = blockIdx.y * 128;
  const int l15 = lane & 15, lg = lane >> 4;

  f32x4 acc[4][4] = {};

  for (int k0 = 0; k0 < BDIM; k0 += 64) {
    for (int j = 0; j < 4; ++j) {
      int o = (w * 4 + j) * 1024 + lane * 16;
      int row = o >> 7;
      int kb = o & 127;
      ushort8 av = *(const ushort8*)(A + (size_t)(m0 + row) * BDIM + k0 + (kb >> 1));
      ushort8 bv = *(const ushort8*)(BT + (size_t)(n0 + row) * BDIM + k0 + (kb >> 1));
      int dst = row * 128 + (kb ^ ((row & 7) << 4));
      *(ushort8*)((char*)As + dst) = av;
      *(ushort8*)((char*)Bs + dst) = bv;
    }
    __syncthreads();
    for (int ks = 0; ks < 64; ks += 32) {
      int kb = (ks + lg * 8) * 2;
      short8 a[4], b[4];
      for (int mi = 0; mi < 4; ++mi) {
        int row = wr * 64 + mi * 16 + l15;
        a[mi] = *(const short8*)((const char*)As + row * 128 + (kb ^ ((row & 7) << 4)));
      }
      for (int nj = 0; nj < 4; ++nj) {
        int row = wc * 64 + nj * 16 + l15;
        b[nj] = *(const short8*)((const char*)Bs + row * 128 + (kb ^ ((row & 7) << 4)));
      }
      for (int mi = 0; mi < 4; ++mi)
        for (int nj = 0; nj < 4; ++nj)
          acc[mi][nj] = __builtin_amdgcn_mfma_f32_16x16x32_bf16(a[mi], b[nj], acc[mi][nj], 0, 0, 0);
    }
    __syncthreads();
  }
  for (int mi = 0; mi < 4; ++mi)
    for (int nj = 0; nj < 4; ++nj) {
      int m = m0 + wr * 64 + mi * 16 + lg * 4;
      int n = n0 + wc * 64 + nj * 16 + l15;
      for (int r = 0; r < 4; ++r) {
        if constexpr (F32OUT)
          ((float*)Cv)[(size_t)(m + r) * BDIM + n] = acc[mi][nj][r];
        else
          ((unsigned short*)Cv)[(size_t)(m + r) * BDIM + n] = f2bf(acc[mi][nj][r]);
      }
    }
}

// ---------------- flash attention (causal), swapped-MFMA structure ----------------
// block: 128 q-rows of one (b,h); 4 waves x 32 rows; KV tiles of 64.
// QK^T computed as mfma(K,Q) -> C'[kv][q]: lane owns ONE q (col=l15), 16 kv in-lane
// => softmax reduce = in-lane + 2 shfls; P written as b64; PV = mfma(VT,P) -> C[d][q]
// keeps q=l15 so rescale/normalize are lane-uniform and O stores are b64.
__global__ __launch_bounds__(256) void attn(const unsigned short* __restrict__ Qg,
                                            const unsigned short* __restrict__ Kg,
                                            const unsigned short* __restrict__ Vg,
                                            unsigned short* __restrict__ Og) {
  __shared__ __align__(16) unsigned short Sbuf[16384];  // 32 KB total
  unsigned short* Ks  = Sbuf;          // [64 kv][64 d]   swz (row&7)<<4
  unsigned short* VTs = Sbuf + 4096;   // [64 d][64 kv]   swzV ((d&7)^(d>>3))<<4
  unsigned short* Ps  = Sbuf + 8192;   // [128 q][64 kv]  swz (row&7)<<4

  const int tid = threadIdx.x;
  const int lane = tid & 63;
  const int w = tid >> 6;
  const int l15 = lane & 15, lg = lane >> 4;
  const int q0 = blockIdx.x * 128;
  const int bh = blockIdx.y;
  const size_t base = ((size_t)(bh >> 4) * SEQ) * BDIM + (size_t)(bh & 15) * 64;

  // ---- stage Q tile [128][64] transiently into Sbuf, pull frags, then reuse ----
  for (int j = 0; j < 4; ++j) {
    int o = (w * 4 + j) * 1024 + lane * 16;
    int row = o >> 7;
    int kb = o & 127;
    ushort8 qv = *(const ushort8*)(Qg + base + (size_t)(q0 + row) * BDIM + (kb >> 1));
    *(ushort8*)((char*)Sbuf + row * 128 + (kb ^ ((row & 7) << 4))) = qv;
  }
  __syncthreads();
  short8 qf[2][2];
  for (int mi = 0; mi < 2; ++mi)
    for (int ks = 0; ks < 2; ++ks) {
      int row = w * 32 + mi * 16 + l15;
      int kb = ks * 64 + lg * 16;
      qf[mi][ks] = *(const short8*)((const char*)Sbuf + row * 128 + (kb ^ ((row & 7) << 4)));
    }
  __syncthreads();  // Sbuf free for K/VT/P

  float mrow[2] = {NEGBIG, NEGBIG}, lrow[2] = {0.f, 0.f};
  f32x4 oacc[2][4] = {};  // [mi][di]: row d=di*16+4lg+r, col q=l15

  const int ntiles = (q0 >> 6) + 2;
  for (int t = 0; t < ntiles; ++t) {
    const int kv0 = t * 64;
    // stage K [64][64] (b128 reg-staged, swizzled)
    for (int j = 0; j < 2; ++j) {
      int o = (w * 2 + j) * 1024 + lane * 16;
      int row = o >> 7;
      int kb = o & 127;
      ushort8 kv8 = *(const ushort8*)(Kg + base + (size_t)(kv0 + row) * BDIM + (kb >> 1));
      *(ushort8*)((char*)Ks + row * 128 + (kb ^ ((row & 7) << 4))) = kv8;
    }
    // stage V^T [d][kv]: kv-pair packed b32 writes, swzV
    {
      int p = tid >> 3, dc8 = tid & 7;
      const unsigned short* vs = Vg + base + (size_t)(kv0 + 2 * p) * BDIM + dc8 * 8;
      ushort8 v0 = *(const ushort8*)vs;
      ushort8 v1 = *(const ushort8*)(vs + BDIM);
      for (int e = 0; e < 8; ++e) {
        int d = dc8 * 8 + e;
        unsigned int pk = (unsigned int)v0[e] | ((unsigned int)v1[e] << 16);
        *(unsigned int*)((char*)VTs + d * 128 + ((4 * p) ^ ((((d & 7) ^ (d >> 3)) & 7) << 4))) = pk;
      }
    }
    __syncthreads();

    if (kv0 <= q0 + w * 32 + 31) {  // wave-uniform causal skip
      // QK^T swapped -> s2[mi][kvj]: lane col q=l15, rows kv=kvj*16+4lg+r
      f32x4 s2[2][4];
      for (int kvj = 0; kvj < 4; ++kvj) {
        int row = kvj * 16 + l15;
        int sz = (row & 7) << 4;
        short8 kf0 = *(const short8*)((const char*)Ks + row * 128 + ((lg * 16) ^ sz));
        short8 kf1 = *(const short8*)((const char*)Ks + row * 128 + ((64 + lg * 16) ^ sz));
        for (int mi = 0; mi < 2; ++mi) {
          f32x4 z = {};
          z = __builtin_amdgcn_mfma_f32_16x16x32_bf16(kf0, qf[mi][0], z, 0, 0, 0);
          z = __builtin_amdgcn_mfma_f32_16x16x32_bf16(kf1, qf[mi][1], z, 0, 0, 0);
          s2[mi][kvj] = z;
        }
      }
      for (int mi = 0; mi < 2; ++mi) {
        const int qc = q0 + w * 32 + mi * 16 + l15;
        float mx = NEGBIG;
        for (int kvj = 0; kvj < 4; ++kvj)
          for (int r = 0; r < 4; ++r) {
            int kv = kv0 + kvj * 16 + 4 * lg + r;
            float v = s2[mi][kvj][r] * 0.125f;
            if (kv > qc) v = NEGBIG;
            s2[mi][kvj][r] = v;
            mx = fmaxf(mx, v);
          }
        mx = fmaxf(mx, __shfl_xor(mx, 16));
        mx = fmaxf(mx, __shfl_xor(mx, 32));
        float mnew = fmaxf(mrow[mi], mx);
        float sc = __expf(mrow[mi] - mnew);  // arg <= 0
        mrow[mi] = mnew;
        float rs = 0.f;
        for (int kvj = 0; kvj < 4; ++kvj)
          for (int r = 0; r < 4; ++r) {
            float p = __expf(s2[mi][kvj][r] - mnew);  // masked -> 0
            s2[mi][kvj][r] = p;
            rs += p;
          }
        rs += __shfl_xor(rs, 16);
        rs += __shfl_xor(rs, 32);
        lrow[mi] = lrow[mi] * sc + rs;
        for (int di = 0; di < 4; ++di)
          for (int r = 0; r < 4; ++r) oacc[mi][di][r] *= sc;
        // P -> LDS: lane's 4 consecutive kv per kvj = one b64 write (own rows only)
        int prow = w * 32 + mi * 16 + l15;
        int psz = (prow & 7) << 4;
        for (int kvj = 0; kvj < 4; ++kvj) {
          bf16x4 pk;
          pk[0] = f2bf(s2[mi][kvj][0]); pk[1] = f2bf(s2[mi][kvj][1]);
          pk[2] = f2bf(s2[mi][kvj][2]); pk[3] = f2bf(s2[mi][kvj][3]);
          *(bf16x4*)((char*)Ps + prow * 128 + ((kvj * 32 + lg * 8) ^ psz)) = pk;
        }
      }
      // PV swapped: oacc[mi][di] = mfma(VT-frag, P-frag) -> C[d][q]
      for (int ks = 0; ks < 2; ++ks) {
        short8 pa[2], vf[4];
        for (int mi = 0; mi < 2; ++mi) {
          int row = w * 32 + mi * 16 + l15;
          pa[mi] = *(const short8*)((const char*)Ps + row * 128 +
                                    ((ks * 64 + lg * 16) ^ ((row & 7) << 4)));
        }
        for (int di = 0; di < 4; ++di) {
          int d = di * 16 + l15;
          vf[di] = *(const short8*)((const char*)VTs + d * 128 +
                                    ((ks * 64 + lg * 16) ^ ((((d & 7) ^ (d >> 3)) & 7) << 4)));
        }
        for (int mi = 0; mi < 2; ++mi)
          for (int di = 0; di < 4; ++di)
            oacc[mi][di] = __builtin_amdgcn_mfma_f32_16x16x32_bf16(vf[di], pa[mi], oacc[mi][di], 0, 0, 0);
      }
    }
    __syncthreads();
  }

  // epilogue: lane col q, rows d=di*16+4lg+r -> 4 consecutive d = b64 stores
  for (int mi = 0; mi < 2; ++mi) {
    float inv = 1.0f / lrow[mi];
    int qrow = q0 + w * 32 + mi * 16 + l15;
    for (int di = 0; di < 4; ++di) {
      bf16x4 ov;
      for (int r = 0; r < 4; ++r) ov[r] = f2bf(oacc[mi][di][r] * inv);
      *(bf16x4*)(Og + base + (size_t)qrow * BDIM + di * 16 + 4 * lg) = ov;
    }
  }
}

extern "C" void kernel_launch(void* const* d_in, const int* in_sizes, int n_in,
                              void* d_out, int out_size, void* d_ws, size_t ws_size,
                              hipStream_t stream) {
  const float* X  = (const float*)d_in[0];
  const float* Wq = (const float*)d_in[1];
  const float* Wk = (const float*)d_in[2];
  const float* Wv = (const float*)d_in[3];
  const float* Wo = (const float*)d_in[4];

  const size_t WSZ = (size_t)1024 * 1024;
  const size_t MSZ = (size_t)8192 * 1024;
  const size_t need = (4 * WSZ + 4 * MSZ) * 2;  // 72 MB
  if (ws_size < need) return;

  unsigned short* ws = (unsigned short*)d_ws;
  unsigned short* WqT = ws;
  unsigned short* WkT = WqT + WSZ;
  unsigned short* WvT = WkT + WSZ;
  unsigned short* WoT = WvT + WSZ;
  unsigned short* Qw  = WoT + WSZ;
  unsigned short* Kw  = Qw + MSZ;
  unsigned short* Vw  = Kw + MSZ;
  unsigned short* Ow  = Vw + MSZ;
  unsigned short* Xb  = (unsigned short*)d_out;  // scratch; dead before final GEMM

  dim3 tb(32, 8);
  dim3 tg(32, 32);
  wtrans<<<tg, tb, 0, stream>>>(Wq, WqT);
  wtrans<<<tg, tb, 0, stream>>>(Wk, WkT);
  wtrans<<<tg, tb, 0, stream>>>(Wv, WvT);
  wtrans<<<tg, tb, 0, stream>>>(Wo, WoT);

  cvt_f32_bf16<<<(8192 * 1024) / (256 * 8), 256, 0, stream>>>(X, Xb);

  dim3 gg(64, 8);
  gemm_bt<false><<<gg, 256, 0, stream>>>(Xb, WqT, Qw);
  gemm_bt<false><<<gg, 256, 0, stream>>>(Xb, WkT, Kw);
  gemm_bt<false><<<gg, 256, 0, stream>>>(Xb, WvT, Vw);

  attn<<<dim3(16, 64), 256, 0, stream>>>(Qw, Kw, Vw, Ow);

  gemm_bt<true><<<gg, 256, 0, stream>>>(Ow, WoT, d_out);
}

// Round 8
// 216.618 us; speedup vs baseline: 1.7124x; 1.2922x over previous
//
#include <hip/hip_runtime.h>
#include <hip/hip_bf16.h>

typedef __attribute__((ext_vector_type(8))) short short8;
typedef __attribute__((ext_vector_type(8))) unsigned short ushort8;
typedef __attribute__((ext_vector_type(4))) unsigned short bf16x4;
typedef __attribute__((ext_vector_type(4))) float f32x4;

#define BDIM 1024
#define SEQ  2048
#define NHD  16
#define NEGBIG (-1.0e30f)

__device__ __forceinline__ unsigned short f2bf(float x) {
  union { __hip_bfloat16 h; unsigned short u; } cv;
  cv.h = __float2bfloat16(x);
  return cv.u;
}

// ---------------- f32 -> bf16 conversion (X), 8 elems/lane ----------------
__global__ __launch_bounds__(256) void cvt_f32_bf16(const float* __restrict__ src,
                                                    unsigned short* __restrict__ dst) {
  int i = (blockIdx.x * 256 + threadIdx.x) * 8;
  float4 a = *(const float4*)(src + i);
  float4 b = *(const float4*)(src + i + 4);
  ushort8 o;
  o[0] = f2bf(a.x); o[1] = f2bf(a.y); o[2] = f2bf(a.z); o[3] = f2bf(a.w);
  o[4] = f2bf(b.x); o[5] = f2bf(b.y); o[6] = f2bf(b.z); o[7] = f2bf(b.w);
  *(ushort8*)(dst + i) = o;
}

// ---------------- weight transpose+convert: dst[n][k] = bf16(src[k][n]) ----------------
__global__ __launch_bounds__(256) void wtrans(const float* __restrict__ src,
                                              unsigned short* __restrict__ dst) {
  __shared__ float t[32][33];
  int tx = threadIdx.x, ty = threadIdx.y;
  int c0 = blockIdx.x * 32, r0 = blockIdx.y * 32;
  for (int i = ty; i < 32; i += 8)
    t[i][tx] = src[(size_t)(r0 + i) * BDIM + c0 + tx];
  __syncthreads();
  for (int i = ty; i < 32; i += 8)
    dst[(size_t)(c0 + i) * BDIM + r0 + tx] = f2bf(t[tx][i]);
}

// ---------------- GEMM: C[M][1024] = A[M][1024] * W, given WT[n][k] (bf16 in) --------
template <bool F32OUT>
__global__ __launch_bounds__(256) void gemm_bt(const unsigned short* __restrict__ A,
                                               const unsigned short* __restrict__ BT,
                                               void* __restrict__ Cv) {
  __shared__ __align__(16) unsigned short As[128 * 64];
  __shared__ __align__(16) unsigned short Bs[128 * 64];
  const int tid = threadIdx.x;
  const int lane = tid & 63;
  const int w = tid >> 6;
  const int wr = w >> 1, wc = w & 1;
  const int m0 = blockIdx.x * 128;
  const int n0 = blockIdx.y * 128;
  const int l15 = lane & 15, lg = lane >> 4;

  f32x4 acc[4][4] = {};

  for (int k0 = 0; k0 < BDIM; k0 += 64) {
    for (int j = 0; j < 4; ++j) {
      int o = (w * 4 + j) * 1024 + lane * 16;
      int row = o >> 7;
      int kb = o & 127;
      ushort8 av = *(const ushort8*)(A + (size_t)(m0 + row) * BDIM + k0 + (kb >> 1));
      ushort8 bv = *(const ushort8*)(BT + (size_t)(n0 + row) * BDIM + k0 + (kb >> 1));
      int dst = row * 128 + (kb ^ ((row & 7) << 4));
      *(ushort8*)((char*)As + dst) = av;
      *(ushort8*)((char*)Bs + dst) = bv;
    }
    __syncthreads();
    for (int ks = 0; ks < 64; ks += 32) {
      int kb = (ks + lg * 8) * 2;
      short8 a[4], b[4];
      for (int mi = 0; mi < 4; ++mi) {
        int row = wr * 64 + mi * 16 + l15;
        a[mi] = *(const short8*)((const char*)As + row * 128 + (kb ^ ((row & 7) << 4)));
      }
      for (int nj = 0; nj < 4; ++nj) {
        int row = wc * 64 + nj * 16 + l15;
        b[nj] = *(const short8*)((const char*)Bs + row * 128 + (kb ^ ((row & 7) << 4)));
      }
      for (int mi = 0; mi < 4; ++mi)
        for (int nj = 0; nj < 4; ++nj)
          acc[mi][nj] = __builtin_amdgcn_mfma_f32_16x16x32_bf16(a[mi], b[nj], acc[mi][nj], 0, 0, 0);
    }
    __syncthreads();
  }
  for (int mi = 0; mi < 4; ++mi)
    for (int nj = 0; nj < 4; ++nj) {
      int m = m0 + wr * 64 + mi * 16 + lg * 4;
      int n = n0 + wc * 64 + nj * 16 + l15;
      for (int r = 0; r < 4; ++r) {
        if constexpr (F32OUT)
          ((float*)Cv)[(size_t)(m + r) * BDIM + n] = acc[mi][nj][r];
        else
          ((unsigned short*)Cv)[(size_t)(m + r) * BDIM + n] = f2bf(acc[mi][nj][r]);
      }
    }
}

// ---------------- flash attention (causal), swapped-MFMA + paired q-tiles ----------------
// block: q-tile PAIR (bx, 15-bx) of one (b,h) -> uniform 34 kv-tiles/block (load balance).
// 4 waves x 32 rows; KV tiles of 64. QK^T as mfma(K,Q) -> C'[kv][q]: lane owns ONE q
// (col=l15), 16 kv in-lane => softmax = in-lane + 2 shfls; P stored b64; PV = mfma(VT,P)
// -> C[d][q] keeps q=l15 so rescale/normalize lane-uniform, O stores b64.
__global__ __launch_bounds__(256) void attn(const unsigned short* __restrict__ Qg,
                                            const unsigned short* __restrict__ Kg,
                                            const unsigned short* __restrict__ Vg,
                                            unsigned short* __restrict__ Og) {
  __shared__ __align__(16) unsigned short Sbuf[16384];  // 32 KB total
  unsigned short* Ks  = Sbuf;          // [64 kv][64 d]   swz (row&7)<<4
  unsigned short* VTs = Sbuf + 4096;   // [64 d][64 kv]   swzV ((d&7)^(d>>3))<<4
  unsigned short* Ps  = Sbuf + 8192;   // [128 q][64 kv]  swz (row&7)<<4

  const int tid = threadIdx.x;
  const int lane = tid & 63;
  const int w = tid >> 6;
  const int l15 = lane & 15, lg = lane >> 4;
  const int bh = blockIdx.y;
  const size_t base = ((size_t)(bh >> 4) * SEQ) * BDIM + (size_t)(bh & 15) * 64;

  for (int half = 0; half < 2; ++half) {
    const int qt = half == 0 ? (int)blockIdx.x : 15 - (int)blockIdx.x;
    const int q0 = qt * 128;

    // ---- stage Q tile [128][64] transiently into Sbuf, pull frags, then reuse ----
    for (int j = 0; j < 4; ++j) {
      int o = (w * 4 + j) * 1024 + lane * 16;
      int row = o >> 7;
      int kb = o & 127;
      ushort8 qv = *(const ushort8*)(Qg + base + (size_t)(q0 + row) * BDIM + (kb >> 1));
      *(ushort8*)((char*)Sbuf + row * 128 + (kb ^ ((row & 7) << 4))) = qv;
    }
    __syncthreads();
    short8 qf[2][2];
    for (int mi = 0; mi < 2; ++mi)
      for (int ks = 0; ks < 2; ++ks) {
        int row = w * 32 + mi * 16 + l15;
        int kb = ks * 64 + lg * 16;
        qf[mi][ks] = *(const short8*)((const char*)Sbuf + row * 128 + (kb ^ ((row & 7) << 4)));
      }
    __syncthreads();  // Sbuf free for K/VT/P

    float mrow[2] = {NEGBIG, NEGBIG}, lrow[2] = {0.f, 0.f};
    f32x4 oacc[2][4] = {};  // [mi][di]: row d=di*16+4lg+r, col q=l15

    const int ntiles = qt * 2 + 2;
    for (int t = 0; t < ntiles; ++t) {
      const int kv0 = t * 64;
      // stage K [64][64] (b128 reg-staged, swizzled)
      for (int j = 0; j < 2; ++j) {
        int o = (w * 2 + j) * 1024 + lane * 16;
        int row = o >> 7;
        int kb = o & 127;
        ushort8 kv8 = *(const ushort8*)(Kg + base + (size_t)(kv0 + row) * BDIM + (kb >> 1));
        *(ushort8*)((char*)Ks + row * 128 + (kb ^ ((row & 7) << 4))) = kv8;
      }
      // stage V^T [d][kv]: kv-pair packed b32 writes, swzV
      {
        int p = tid >> 3, dc8 = tid & 7;
        const unsigned short* vs = Vg + base + (size_t)(kv0 + 2 * p) * BDIM + dc8 * 8;
        ushort8 v0 = *(const ushort8*)vs;
        ushort8 v1 = *(const ushort8*)(vs + BDIM);
        for (int e = 0; e < 8; ++e) {
          int d = dc8 * 8 + e;
          unsigned int pk = (unsigned int)v0[e] | ((unsigned int)v1[e] << 16);
          *(unsigned int*)((char*)VTs + d * 128 + ((4 * p) ^ ((((d & 7) ^ (d >> 3)) & 7) << 4))) = pk;
        }
      }
      __syncthreads();

      if (kv0 <= q0 + w * 32 + 31) {  // wave-uniform causal skip
        // QK^T swapped -> s2[mi][kvj]: lane col q=l15, rows kv=kvj*16+4lg+r
        f32x4 s2[2][4];
        for (int kvj = 0; kvj < 4; ++kvj) {
          int row = kvj * 16 + l15;
          int sz = (row & 7) << 4;
          short8 kf0 = *(const short8*)((const char*)Ks + row * 128 + ((lg * 16) ^ sz));
          short8 kf1 = *(const short8*)((const char*)Ks + row * 128 + ((64 + lg * 16) ^ sz));
          for (int mi = 0; mi < 2; ++mi) {
            f32x4 z = {};
            z = __builtin_amdgcn_mfma_f32_16x16x32_bf16(kf0, qf[mi][0], z, 0, 0, 0);
            z = __builtin_amdgcn_mfma_f32_16x16x32_bf16(kf1, qf[mi][1], z, 0, 0, 0);
            s2[mi][kvj] = z;
          }
        }
        for (int mi = 0; mi < 2; ++mi) {
          const int qc = q0 + w * 32 + mi * 16 + l15;
          float mx = NEGBIG;
          for (int kvj = 0; kvj < 4; ++kvj)
            for (int r = 0; r < 4; ++r) {
              int kv = kv0 + kvj * 16 + 4 * lg + r;
              float v = s2[mi][kvj][r] * 0.125f;
              if (kv > qc) v = NEGBIG;
              s2[mi][kvj][r] = v;
              mx = fmaxf(mx, v);
            }
          mx = fmaxf(mx, __shfl_xor(mx, 16));
          mx = fmaxf(mx, __shfl_xor(mx, 32));
          float mnew = fmaxf(mrow[mi], mx);
          float sc = __expf(mrow[mi] - mnew);  // arg <= 0
          mrow[mi] = mnew;
          float rs = 0.f;
          for (int kvj = 0; kvj < 4; ++kvj)
            for (int r = 0; r < 4; ++r) {
              float p = __expf(s2[mi][kvj][r] - mnew);  // masked -> 0
              s2[mi][kvj][r] = p;
              rs += p;
            }
          rs += __shfl_xor(rs, 16);
          rs += __shfl_xor(rs, 32);
          lrow[mi] = lrow[mi] * sc + rs;
          for (int di = 0; di < 4; ++di)
            for (int r = 0; r < 4; ++r) oacc[mi][di][r] *= sc;
          // P -> LDS: lane's 4 consecutive kv per kvj = one b64 write (own rows only)
          int prow = w * 32 + mi * 16 + l15;
          int psz = (prow & 7) << 4;
          for (int kvj = 0; kvj < 4; ++kvj) {
            bf16x4 pk;
            pk[0] = f2bf(s2[mi][kvj][0]); pk[1] = f2bf(s2[mi][kvj][1]);
            pk[2] = f2bf(s2[mi][kvj][2]); pk[3] = f2bf(s2[mi][kvj][3]);
            *(bf16x4*)((char*)Ps + prow * 128 + ((kvj * 32 + lg * 8) ^ psz)) = pk;
          }
        }
        // PV swapped: oacc[mi][di] = mfma(VT-frag, P-frag) -> C[d][q]
        for (int ks = 0; ks < 2; ++ks) {
          short8 pa[2], vf[4];
          for (int mi = 0; mi < 2; ++mi) {
            int row = w * 32 + mi * 16 + l15;
            pa[mi] = *(const short8*)((const char*)Ps + row * 128 +
                                      ((ks * 64 + lg * 16) ^ ((row & 7) << 4)));
          }
          for (int di = 0; di < 4; ++di) {
            int d = di * 16 + l15;
            vf[di] = *(const short8*)((const char*)VTs + d * 128 +
                                      ((ks * 64 + lg * 16) ^ ((((d & 7) ^ (d >> 3)) & 7) << 4)));
          }
          for (int mi = 0; mi < 2; ++mi)
            for (int di = 0; di < 4; ++di)
              oacc[mi][di] = __builtin_amdgcn_mfma_f32_16x16x32_bf16(vf[di], pa[mi], oacc[mi][di], 0, 0, 0);
        }
      }
      __syncthreads();
    }

    // epilogue: lane col q, rows d=di*16+4lg+r -> 4 consecutive d = b64 stores
    for (int mi = 0; mi < 2; ++mi) {
      float inv = 1.0f / lrow[mi];
      int qrow = q0 + w * 32 + mi * 16 + l15;
      for (int di = 0; di < 4; ++di) {
        bf16x4 ov;
        for (int r = 0; r < 4; ++r) ov[r] = f2bf(oacc[mi][di][r] * inv);
        *(bf16x4*)(Og + base + (size_t)qrow * BDIM + di * 16 + 4 * lg) = ov;
      }
    }
  }
}

extern "C" void kernel_launch(void* const* d_in, const int* in_sizes, int n_in,
                              void* d_out, int out_size, void* d_ws, size_t ws_size,
                              hipStream_t stream) {
  const float* X  = (const float*)d_in[0];
  const float* Wq = (const float*)d_in[1];
  const float* Wk = (const float*)d_in[2];
  const float* Wv = (const float*)d_in[3];
  const float* Wo = (const float*)d_in[4];

  const size_t WSZ = (size_t)1024 * 1024;
  const size_t MSZ = (size_t)8192 * 1024;
  const size_t need = (4 * WSZ + 4 * MSZ) * 2;  // 72 MB
  if (ws_size < need) return;

  unsigned short* ws = (unsigned short*)d_ws;
  unsigned short* WqT = ws;
  unsigned short* WkT = WqT + WSZ;
  unsigned short* WvT = WkT + WSZ;
  unsigned short* WoT = WvT + WSZ;
  unsigned short* Qw  = WoT + WSZ;
  unsigned short* Kw  = Qw + MSZ;
  unsigned short* Vw  = Kw + MSZ;
  unsigned short* Ow  = Vw + MSZ;
  unsigned short* Xb  = (unsigned short*)d_out;  // scratch; dead before final GEMM

  dim3 tb(32, 8);
  dim3 tg(32, 32);
  wtrans<<<tg, tb, 0, stream>>>(Wq, WqT);
  wtrans<<<tg, tb, 0, stream>>>(Wk, WkT);
  wtrans<<<tg, tb, 0, stream>>>(Wv, WvT);
  wtrans<<<tg, tb, 0, stream>>>(Wo, WoT);

  cvt_f32_bf16<<<(8192 * 1024) / (256 * 8), 256, 0, stream>>>(X, Xb);

  dim3 gg(64, 8);
  gemm_bt<false><<<gg, 256, 0, stream>>>(Xb, WqT, Qw);
  gemm_bt<false><<<gg, 256, 0, stream>>>(Xb, WkT, Kw);
  gemm_bt<false><<<gg, 256, 0, stream>>>(Xb, WvT, Vw);

  attn<<<dim3(8, 64), 256, 0, stream>>>(Qw, Kw, Vw, Ow);

  gemm_bt<true><<<gg, 256, 0, stream>>>(Ow, WoT, d_out);
}